// Round 16
// baseline (141.192 us; speedup 1.0000x reference)
//
#include <hip/hip_runtime.h>
#include <math.h>

#define Bsz 8
#define Cch 512
#define Npx 1024
#define TOPK 12
#define BN (Bsz * Npx)

typedef __attribute__((ext_vector_type(8))) short bf16x8;
typedef __attribute__((ext_vector_type(4))) float f32x4;

__device__ __forceinline__ unsigned short f2bf(float x) {
    unsigned u = __float_as_uint(x);
    u += 0x7FFF + ((u >> 16) & 1);
    return (unsigned short)(u >> 16);
}
__device__ __forceinline__ float bf2f(unsigned short h) {
    return __uint_as_float(((unsigned)h) << 16);
}

// ---------------- reduction helpers ----------------
__device__ __forceinline__ float warp_sum64(float v) {
    for (int o = 32; o > 0; o >>= 1) v += __shfl_down(v, o);
    return v;
}
__device__ __forceinline__ float block_sum512(float v, float* s8) {
    v = warp_sum64(v);
    int lane = threadIdx.x & 63, w = threadIdx.x >> 6;
    __syncthreads();
    if (lane == 0) s8[w] = v;
    __syncthreads();
    float r = 0.f;
    #pragma unroll
    for (int k = 0; k < 8; k++) r += s8[k];
    return r;
}

// ---------------- 1: masked average pool (float4, single-barrier) -------------
// grid (Cch, Bsz), block 256
__global__ void k_pool(const float* __restrict__ sf, const int* __restrict__ mask,
                       float* __restrict__ FPo, float* __restrict__ BPo) {
    __shared__ float s4a[4], s4b[4], s4c[4];
    int c = blockIdx.x, b = blockIdx.y, t = threadIdx.x;
    const float4* f4 = (const float4*)(sf + ((size_t)b * Cch + c) * Npx);
    const int4* m4 = (const int4*)(mask + (size_t)b * Npx);
    float4 v = f4[t];
    int4 m = m4[t];
    float sumf = (m.x == 1 ? v.x : 0.f) + (m.y == 1 ? v.y : 0.f)
               + (m.z == 1 ? v.z : 0.f) + (m.w == 1 ? v.w : 0.f);
    float tot = v.x + v.y + v.z + v.w;
    float cf = (float)((m.x == 1) + (m.y == 1) + (m.z == 1) + (m.w == 1));
    sumf = warp_sum64(sumf);
    tot  = warp_sum64(tot);
    cf   = warp_sum64(cf);
    int lane = t & 63, w = t >> 6;
    if (lane == 0) { s4a[w] = sumf; s4b[w] = tot; s4c[w] = cf; }
    __syncthreads();
    if (t == 0) {
        float sA = s4a[0] + s4a[1] + s4a[2] + s4a[3];
        float sB = s4b[0] + s4b[1] + s4b[2] + s4b[3];
        float sC = s4c[0] + s4c[1] + s4c[2] + s4c[3];
        FPo[b * Cch + c] = sA / (sC + 1e-5f);
        BPo[b * Cch + c] = (sB - sA) / ((1024.f - sC) + 1e-5f);
    }
}

// ---------------- 2: pred logit + bf16 cast (block 512: 16 thr/pixel) ---------
// grid (Npx/32, Bsz), block 512.
__global__ void __launch_bounds__(512) k_predcast(const float* __restrict__ fq,
                       const float* __restrict__ FP, const float* __restrict__ BP,
                       float* __restrict__ dsim, float* __restrict__ invn,
                       unsigned short* __restrict__ Ft) {
    __shared__ float sFP[Cch], sBP[Cch], s8[8];
    __shared__ float rdf[16][32], rdb[16][32], rqq[16][32];
    __shared__ unsigned short S[32][522];   // odd dword stride -> conflict-free
    int b = blockIdx.y, t = threadIdx.x;
    int tx = t & 31, ty = t >> 5;           // ty in [0,16)
    int p0 = blockIdx.x * 32;
    int p = p0 + tx;
    sFP[t] = FP[b * Cch + t];
    sBP[t] = BP[b * Cch + t];
    __syncthreads();
    float nf = sqrtf(block_sum512(sFP[t] * sFP[t], s8));
    float nb = sqrtf(block_sum512(sBP[t] * sBP[t], s8));
    const float* q = fq + (size_t)b * Cch * Npx + p;
    float df = 0.f, db = 0.f, qq = 0.f;
    int c0 = ty * 32;
    #pragma unroll 4
    for (int c = 0; c < 32; c += 2) {
        float v0 = q[(size_t)(c0 + c) * Npx];
        float v1 = q[(size_t)(c0 + c + 1) * Npx];
        df += v0 * sFP[c0 + c] + v1 * sFP[c0 + c + 1];
        db += v0 * sBP[c0 + c] + v1 * sBP[c0 + c + 1];
        qq += v0 * v0 + v1 * v1;
        unsigned pk = (unsigned)f2bf(v0) | ((unsigned)f2bf(v1) << 16);
        *(unsigned*)&S[tx][c0 + c] = pk;
    }
    rdf[ty][tx] = df; rdb[ty][tx] = db; rqq[ty][tx] = qq;
    __syncthreads();
    for (int s = 8; s > 0; s >>= 1) {
        if (ty < s) {
            rdf[ty][tx] += rdf[ty + s][tx];
            rdb[ty][tx] += rdb[ty + s][tx];
            rqq[ty][tx] += rqq[ty + s][tx];
        }
        __syncthreads();
    }
    if (ty == 0) {
        float nq = sqrtf(rqq[0][tx]);
        float simf = 10.f * rdf[0][tx] / fmaxf(nq * nf, 1e-8f);
        float simb = 10.f * rdb[0][tx] / fmaxf(nq * nb, 1e-8f);
        dsim[b * Npx + p] = simf - simb;
        invn[b * Npx + p] = 1.f / nq;
    }
    // write Ft rows (coalesced dword stores, conflict-free LDS dword reads)
    int w = t >> 6, lane = t & 63;           // 8 waves
    unsigned short* FtB = Ft + (size_t)b * Npx * Cch;
    for (int pr = w; pr < 32; pr += 8) {
        unsigned* dst = (unsigned*)(FtB + (size_t)(p0 + pr) * Cch);
        #pragma unroll
        for (int it = 0; it < 4; it++) {
            int d = it * 64 + lane;
            dst[d] = *(const unsigned*)&S[pr][d * 2];
        }
    }
}

// ---------------- 3: select + compact + prototypes + FP1/nf -------------------
// grid (2, Bsz), block 1024 (16 waves). x=0: fg, x=1: bg
__global__ void __launch_bounds__(1024) k_selcompact(const float* __restrict__ dsim,
                        const float* __restrict__ invn,
                        const unsigned short* __restrict__ Ft,
                        const float* __restrict__ FP,
                        int* __restrict__ nsf, int* __restrict__ nsb,
                        int* __restrict__ jf, int* __restrict__ jb,
                        float* __restrict__ ivg,
                        float* __restrict__ fgp, float* __restrict__ bgp,
                        float* __restrict__ FP1, float* __restrict__ nfv) {
    __shared__ int wsum[16];
    __shared__ int sns;
    __shared__ float sProto[16][512];       // 32 KB
    __shared__ float s16f[16];
    int b = blockIdx.y, t = threadIdx.x;
    int lane = t & 63, w = t >> 6;
    bool isf = (blockIdx.x == 0);
    float d = dsim[b * Npx + t];
    float key = isf ? d : -d;
    float thres = isf ? 0.8472979f : 0.4054651f;   // ln(0.7/0.3), ln(0.6/0.4)
    int flag = (key > thres) ? 1 : 0;
    int x = flag;
    #pragma unroll
    for (int o = 1; o < 64; o <<= 1) {
        int y = __shfl_up(x, o);
        if (lane >= o) x += y;
    }
    if (lane == 63) wsum[w] = x;
    __syncthreads();
    int base = 0, total = 0;
    #pragma unroll
    for (int k = 0; k < 16; k++) {
        int s = wsum[k];
        if (k < w) base += s;
        total += s;
    }
    int* jdst = (isf ? jf : jb) + b * Npx;
    if (total == 0) {
        // cold path: top-12 fallback (lower index wins ties)
        __shared__ int   sc[Npx];
        __shared__ float v[Npx];
        __shared__ float rv[Npx];
        __shared__ int   ri[Npx];
        v[t] = key; flag = 0;
        __syncthreads();
        for (int k = 0; k < TOPK; k++) {
            rv[t] = v[t]; ri[t] = t;
            __syncthreads();
            for (int s = 512; s > 0; s >>= 1) {
                if (t < s) {
                    float a = rv[t], bb = rv[t + s];
                    int ia = ri[t], ib = ri[t + s];
                    if (bb > a || (bb == a && ib < ia)) { rv[t] = bb; ri[t] = ib; }
                }
                __syncthreads();
            }
            int win = ri[0];
            if (t == win) { flag = 1; v[t] = -INFINITY; }
            __syncthreads();
        }
        sc[t] = flag;
        __syncthreads();
        for (int off = 1; off < 1024; off <<= 1) {
            int xx = (t >= off) ? sc[t - off] : 0;
            __syncthreads();
            sc[t] += xx;
            __syncthreads();
        }
        if (flag) {
            int pos = sc[t] - 1;
            jdst[pos] = t;
            if (!isf) ivg[b * Npx + pos] = invn[b * Npx + t];
        }
        if (t == 1023) sns = sc[1023];
    } else {
        if (flag) {
            int pos = base + x - 1;
            jdst[pos] = t;
            if (!isf) ivg[b * Npx + pos] = invn[b * Npx + t];
        }
        if (t == 0) sns = total;
    }
    __syncthreads();                         // jdst writes + sns visible to block
    int ns = sns;
    if (t == 0) (isf ? nsf : nsb)[b] = ns;
    // ---- prototype: mean of selected Ft rows (coalesced 1KB row reads) ----
    const unsigned short* FtB = Ft + (size_t)b * Npx * Cch;
    float facc[8] = {0.f, 0.f, 0.f, 0.f, 0.f, 0.f, 0.f, 0.f};
    int k = w;
    int row = (k < ns) ? jdst[k] : 0;
    while (k < ns) {
        int kn = k + 16;
        int rown = (kn < ns) ? jdst[kn] : 0;   // prefetch index
        bf16x8 vv = *(const bf16x8*)&FtB[(size_t)row * Cch + lane * 8];
        #pragma unroll
        for (int e = 0; e < 8; e++) facc[e] += bf2f((unsigned short)vv[e]);
        k = kn; row = rown;
    }
    #pragma unroll
    for (int e = 0; e < 8; e++) sProto[w][lane * 8 + e] = facc[e];
    __syncthreads();
    float fp1 = 0.f;
    if (t < 512) {
        float s = 0.f;
        #pragma unroll
        for (int q = 0; q < 16; q++) s += sProto[q][t];
        float pv = s / (float)ns;
        (isf ? fgp : bgp)[b * Cch + t] = pv;
        if (isf) {
            fp1 = 0.5f * FP[b * Cch + t] + 0.5f * pv;
            FP1[b * Cch + t] = fp1;
        }
    }
    if (isf) {
        // ||FP1|| for the final fg similarity
        float v2 = warp_sum64(fp1 * fp1);
        if (lane == 0) s16f[w] = v2;
        __syncthreads();
        if (t == 0) {
            float nn = 0.f;
            #pragma unroll
            for (int q = 0; q < 16; q++) nn += s16f[q];
            nfv[b] = sqrtf(nn);
        }
    }
}

// ---------------- 4: FUSED gram + softmax + PV + finalize (compacted-j) -------
// grid 256 (1D, batch->XCD swizzle), block 512 (8 waves).
// R16: LDS cut 152 -> 75.1 KB for 2 blocks/CU (launch_bounds(512,4) caps VGPR
// at 128 -> 4 waves/SIMD). sP[32][520] + jh0 half-loop (phase1/denom/PV all
// accumulate linearly across <=512-j halves; single pass for ns<=512 which is
// the practical case). Vt[256][68] with 2 c-half passes in PV (total scatter
// bytes unchanged). Union(Bt2, Vt) = 34816 ushorts exactly.
__global__ void __launch_bounds__(512, 4) k_fused(
        const unsigned short* __restrict__ Ft,
        const int* __restrict__ jb, const int* __restrict__ nsb,
        const float* __restrict__ invn, const float* __restrict__ ivg,
        const float* __restrict__ bgp, const float* __restrict__ FP1,
        const float* __restrict__ nfv, float* __restrict__ out) {
    __shared__ unsigned short U[17408];         // 34.8 KB: Bt2[2][64][136] U Vt[256][68]
    __shared__ unsigned short sP[32][520];      // 33.3 KB attention rows (one j-half)
    __shared__ int   sji[512];
    __shared__ float sfj[512];
    __shared__ float sfp1full[Cch], sbgfull[Cch];
    __shared__ float sfi[32], sden[32];
    __shared__ float spart[32][3];

    unsigned short (*Bt2)[64][136] = (unsigned short(*)[64][136])U;
    unsigned short (*Vt)[68] = (unsigned short(*)[68])U;

    int bid = blockIdx.x;
    int b = bid & 7;                       // batch -> XCD (round-robin heuristic)
    int i0 = (bid >> 3) * 32;
    int tid = threadIdx.x;
    int l = tid & 63, w = tid >> 6;
    int ml = l & 15, quad = l >> 4;
    int ns = nsb[b];
    int K64 = ((((ns + 31) & ~31) + 63) & ~63);

    const unsigned short* FtB = Ft + (size_t)b * Npx * Cch;
    int ig = w & 1, jg = w >> 1;            // 8 waves tile 32i x 64j (phase 1)

    // ---- A-fragments in registers (invariant across j; L2-hot 16B loads) ----
    bf16x8 afr[4][4];
    {
        const unsigned short* aro = FtB + (size_t)(i0 + ig * 16 + ml) * Cch + quad * 8;
        #pragma unroll
        for (int kt = 0; kt < 4; kt++)
            #pragma unroll
            for (int h = 0; h < 4; h++)
                afr[kt][h] = *(const bf16x8*)(aro + kt * 128 + h * 32);
    }

    // ---- constants preload ----
    sfp1full[tid] = FP1[b * Cch + tid];
    sbgfull[tid]  = 0.3f * bgp[b * Cch + tid];
    if (tid < 32) { sfi[tid] = 2.f * invn[b * Npx + i0 + tid]; sden[tid] = 0.f; }
    if (tid < 96) ((float*)spart)[tid] = 0.f;

    int grow = tid >> 4, gk8 = (tid & 15) * 8;  // phase-1 staging coords
    int jp = tid & 31, cgg = tid >> 5;          // phase-2 scatter coords
    f32x4 accp[4][2] = {};                      // [ch*2+cf][iff]

    for (int jh0 = 0; jh0 < K64; jh0 += 512) {
        int JH = min(512, K64 - jh0);
        int TH = JH >> 6;
        // ---- tables for this half ----
        __syncthreads();                    // prev phase2 done reading sji/U
        for (int j = tid; j < JH; j += 512) {
            int gj = jh0 + j;
            sji[j] = (gj < ns) ? jb[b * Npx + gj] : jb[b * Npx];
            sfj[j] = (gj < ns) ? ivg[b * Npx + gj] : 0.f;
        }
        __syncthreads();

        // ---- phase 1: gram -> sP = exp(sim) (bf16); dbuf Bt2, 1 bar/k-chunk --
        for (int j0 = 0; j0 < JH; j0 += 64) {
            const unsigned short* pb0 = FtB + (size_t)sji[j0 + grow] * Cch + gk8;
            const unsigned short* pb1 = FtB + (size_t)sji[j0 + 32 + grow] * Cch + gk8;
            uint4 v0 = *(const uint4*)pb0;
            uint4 v1 = *(const uint4*)pb1;
            f32x4 acc = {};
            #pragma unroll
            for (int kt = 0; kt < 4; kt++) {
                int buf = kt & 1;
                *(uint4*)&Bt2[buf][grow][gk8] = v0;
                *(uint4*)&Bt2[buf][32 + grow][gk8] = v1;
                int kn = (kt + 1) * 128;
                if (kn < Cch) {
                    v0 = *(const uint4*)(pb0 + kn);
                    v1 = *(const uint4*)(pb1 + kn);
                }
                __syncthreads();
                #pragma unroll
                for (int h = 0; h < 4; h++) {
                    bf16x8 bf = *(const bf16x8*)&Bt2[buf][jg * 16 + ml][h * 32 + quad * 8];
                    acc = __builtin_amdgcn_mfma_f32_16x16x32_bf16(afr[kt][h], bf, acc, 0, 0, 0);
                }
            }
            #pragma unroll
            for (int r = 0; r < 4; r++) {
                int il = ig * 16 + quad * 4 + r;
                int jl = jg * 16 + ml;
                float e = (jh0 + j0 + jl < ns) ? __expf(acc[r] * sfi[il] * sfj[j0 + jl]) : 0.f;
                sP[il][j0 + jl] = f2bf(e);
            }
        }
        __syncthreads();

        // ---- denom partial accumulate (same thread per row across halves) ----
        {
            int i = tid >> 4, jj16 = tid & 15;
            float s = 0.f;
            for (int j = jj16; j < JH; j += 16) s += bf2f(sP[i][j]);
            #pragma unroll
            for (int m = 1; m < 16; m <<= 1) s += __shfl_xor(s, m);
            if (jj16 == 0) sden[i] += s;
        }
        __syncthreads();                    // Bt2 reads done; Vt scatter safe

        // ---- phase 2: PV for this half; Vt per (c-half, j-tile) ----
        #pragma unroll
        for (int ch = 0; ch < 2; ch++) {
            const unsigned short* rA = FtB + (size_t)sji[2 * jp] * Cch + ch * 256 + cgg * 16;
            const unsigned short* rB = FtB + (size_t)sji[2 * jp + 1] * Cch + ch * 256 + cgg * 16;
            uint4 a0 = *(const uint4*)rA, a1 = *(const uint4*)(rA + 8);
            uint4 b0 = *(const uint4*)rB, b1 = *(const uint4*)(rB + 8);
            for (int jt = 0; jt < TH; jt++) {
                {   // scatter: Vt[c_local][j] <- rows (2jp,2jp+1), u32-packed
                    unsigned av[8] = {a0.x, a0.y, a0.z, a0.w, a1.x, a1.y, a1.z, a1.w};
                    unsigned bv[8] = {b0.x, b0.y, b0.z, b0.w, b1.x, b1.y, b1.z, b1.w};
                    #pragma unroll
                    for (int d = 0; d < 8; d++) {
                        int c = cgg * 16 + 2 * d;
                        *(unsigned*)&Vt[c][2 * jp]     = (av[d] & 0xFFFFu) | (bv[d] << 16);
                        *(unsigned*)&Vt[c + 1][2 * jp] = (av[d] >> 16) | (bv[d] & 0xFFFF0000u);
                    }
                }
                if (jt + 1 < TH) {          // prefetch next tile's rows
                    rA = FtB + (size_t)sji[(jt + 1) * 64 + 2 * jp] * Cch + ch * 256 + cgg * 16;
                    rB = FtB + (size_t)sji[(jt + 1) * 64 + 2 * jp + 1] * Cch + ch * 256 + cgg * 16;
                    a0 = *(const uint4*)rA; a1 = *(const uint4*)(rA + 8);
                    b0 = *(const uint4*)rB; b1 = *(const uint4*)(rB + 8);
                }
                __syncthreads();            // Vt ready
                int j0 = jt * 64;
                #pragma unroll
                for (int iff = 0; iff < 2; iff++) {
                    bf16x8 p0 = *(const bf16x8*)&sP[iff * 16 + ml][j0 + quad * 8];
                    bf16x8 p1 = *(const bf16x8*)&sP[iff * 16 + ml][j0 + 32 + quad * 8];
                    #pragma unroll
                    for (int cf = 0; cf < 2; cf++) {
                        bf16x8 v0 = *(const bf16x8*)&Vt[w * 32 + cf * 16 + ml][quad * 8];
                        bf16x8 v1 = *(const bf16x8*)&Vt[w * 32 + cf * 16 + ml][32 + quad * 8];
                        accp[ch * 2 + cf][iff] = __builtin_amdgcn_mfma_f32_16x16x32_bf16(v0, p0, accp[ch * 2 + cf][iff], 0, 0, 0);
                        accp[ch * 2 + cf][iff] = __builtin_amdgcn_mfma_f32_16x16x32_bf16(v1, p1, accp[ch * 2 + cf][iff], 0, 0, 0);
                    }
                }
                __syncthreads();            // Vt consumed; next scatter safe
            }
        }
    }

    // ---- epilogue: per-thread similarity partials (runs once) ----
    float sdb[2] = {0.f, 0.f}, snb[2] = {0.f, 0.f}, sdf[2] = {0.f, 0.f};
    #pragma unroll
    for (int iff = 0; iff < 2; iff++) {
        int icol = iff * 16 + ml;
        float rdi = 1.f / sden[icol];
        #pragma unroll
        for (int ch = 0; ch < 2; ch++) {
            #pragma unroll
            for (int cf = 0; cf < 2; cf++) {
                int clb = ch * 256 + w * 32 + cf * 16 + quad * 4;
                const unsigned* qp = (const unsigned*)(FtB + (size_t)(i0 + icol) * Cch + clb);
                unsigned q01 = qp[0], q23 = qp[1];
                float qv[4] = { bf2f((unsigned short)(q01 & 0xFFFFu)),
                                bf2f((unsigned short)(q01 >> 16)),
                                bf2f((unsigned short)(q23 & 0xFFFFu)),
                                bf2f((unsigned short)(q23 >> 16)) };
                #pragma unroll
                for (int r = 0; r < 4; r++) {
                    int cl = clb + r;
                    float loc = accp[ch * 2 + cf][iff][r] * rdi;
                    float bp1 = sbgfull[cl] + 0.7f * loc;
                    sdb[iff] += qv[r] * bp1;
                    snb[iff] += bp1 * bp1;
                    sdf[iff] += qv[r] * sfp1full[cl];
                }
            }
        }
    }
    #pragma unroll
    for (int iff = 0; iff < 2; iff++) {
        float a = sdb[iff], bq = snb[iff], c = sdf[iff];
        a += __shfl_xor(a, 16);  a += __shfl_xor(a, 32);
        bq += __shfl_xor(bq, 16); bq += __shfl_xor(bq, 32);
        c += __shfl_xor(c, 16);  c += __shfl_xor(c, 32);
        if (quad == 0) {
            int icol = iff * 16 + ml;
            atomicAdd(&spart[icol][0], a);
            atomicAdd(&spart[icol][1], bq);
            atomicAdd(&spart[icol][2], c);
        }
    }
    __syncthreads();
    if (tid < 32) {
        float db = spart[tid][0], nb = spart[tid][1], df = spart[tid][2];
        float nq = 2.f / sfi[tid];          // = 1/invn (f32-exact reference norm)
        float sb2 = 10.f * db / fmaxf(nq * sqrtf(nb), 1e-8f);
        float sf2 = 10.f * df / fmaxf(nq * nfv[b], 1e-8f);
        out[((size_t)b * 2) * Npx + i0 + tid] = sb2;
        out[((size_t)b * 2 + 1) * Npx + i0 + tid] = sf2;
    }
}

extern "C" void kernel_launch(void* const* d_in, const int* in_sizes, int n_in,
                              void* d_out, int out_size, void* d_ws, size_t ws_size,
                              hipStream_t stream) {
    const float* fq = (const float*)d_in[0];
    const float* sf = (const float*)d_in[1];
    const int* mask = (const int*)d_in[2];
    float* out = (float*)d_out;

    float* ws = (float*)d_ws;
    float* FP    = ws;                        // B*C
    float* BP    = FP + Bsz * Cch;
    float* fgp   = BP + Bsz * Cch;
    float* bgp   = fgp + Bsz * Cch;
    float* FP1   = bgp + Bsz * Cch;           // B*C
    float* nfv   = FP1 + Bsz * Cch;           // 8
    float* dsim  = nfv + 8;                   // B*N
    float* invn  = dsim + BN;
    float* ivg   = invn + BN;
    int*   nsf   = (int*)(ivg + BN);          // 8
    int*   nsb   = nsf + 8;                   // 8
    int*   jf    = nsb + 8;                   // B*N
    int*   jb    = jf + BN;                   // B*N
    unsigned short* Ft = (unsigned short*)(jb + BN);                     // 8 MB [i][c]

    k_pool<<<dim3(Cch, Bsz), 256, 0, stream>>>(sf, mask, FP, BP);
    k_predcast<<<dim3(Npx / 32, Bsz), 512, 0, stream>>>(fq, FP, BP, dsim, invn, Ft);
    k_selcompact<<<dim3(2, Bsz), 1024, 0, stream>>>(dsim, invn, Ft, FP, nsf, nsb, jf, jb, ivg, fgp, bgp, FP1, nfv);
    k_fused<<<dim3(256), 512, 0, stream>>>(Ft, jb, nsb, invn, ivg, bgp, FP1, nfv, out);
}